// Round 6
// baseline (1462.429 us; speedup 1.0000x reference)
//
#include <hip/hip_runtime.h>
#include <hip/hip_bf16.h>
#include <math.h>

#define NTOK   8192      // B*S tokens
#define NEXP   64
#define EMBD   1024
#define MLPD   2048
#define TOPK   2
#define NFLAT  (NTOK * TOPK)
#define BKD    32        // K tile
#define APAD   40        // LDS row stride (bf16 elems) = 80B
#define BPAD   40
#define MAXCH  8         // max m-chunks of 128 (mean Me=256)

typedef __attribute__((ext_vector_type(4))) float  f32x4;
typedef __attribute__((ext_vector_type(2))) float  f32x2;
typedef __attribute__((ext_vector_type(8))) __bf16 bf16x8;
typedef __attribute__((ext_vector_type(4))) __bf16 bf16x4;

// raw workgroup barrier WITHOUT the __syncthreads() vmcnt(0) drain:
// ds-visibility via lgkmcnt(0); global prefetches stay in flight.
__device__ __forceinline__ void lds_barrier() {
  asm volatile("s_waitcnt lgkmcnt(0)" ::: "memory");
  __builtin_amdgcn_sched_barrier(0);
  __builtin_amdgcn_s_barrier();
}

// ---------------- workspace layout (bytes) ----------------
#define OFF_COUNTS 0
#define OFF_BASE   256
#define OFF_RUN    512
#define OFF_EFLAT  1024
#define OFF_WFLAT  (1024 + 65536)
#define OFF_ROWTOK (1024 + 2 * 65536)
#define OFF_F2R    (1024 + 3 * 65536)
#define OFF_INTER  (1024 + 4 * 65536)                       // bf16 [16384][2048]
#define OFF_OS     (OFF_INTER + (size_t)NFLAT * MLPD * 2)   // out_sorted
#define NEED_F32   (OFF_OS + (size_t)NFLAT * EMBD * 4)

// ---------------- router: logits + top-2 + softmax ----------------
__global__ __launch_bounds__(256) void router_topk(
    const float* __restrict__ x, const float* __restrict__ gk,
    int* __restrict__ e_flat, float* __restrict__ w_flat) {
  int t = blockIdx.x * 4 + (threadIdx.x >> 6);
  int l = threadIdx.x & 63;
  const float* xr = x + (size_t)t * EMBD;
  float acc = 0.f;
  #pragma unroll 8
  for (int i = 0; i < EMBD; ++i)
    acc = fmaf(xr[i], gk[i * NEXP + l], acc);
  float m = acc;
  for (int o = 32; o; o >>= 1) m = fmaxf(m, __shfl_xor(m, o));
  unsigned long long b1 = __ballot(acc == m);
  int i1 = __ffsll(b1) - 1;
  float v2 = (l == i1) ? -INFINITY : acc;
  float m2 = v2;
  for (int o = 32; o; o >>= 1) m2 = fmaxf(m2, __shfl_xor(m2, o));
  unsigned long long b2 = __ballot(v2 == m2);
  int i2 = __ffsll(b2) - 1;
  if (l == 0) {
    float e2 = expf(m2 - m);
    float inv = 1.f / (1.f + e2);
    e_flat[2 * t] = i1;  e_flat[2 * t + 1] = i2;
    w_flat[2 * t] = inv; w_flat[2 * t + 1] = e2 * inv;
  }
}

// ---------------- histogram / scan / scatter ----------------
__global__ void hist_k(const int* __restrict__ ef, int* __restrict__ counts) {
  int j = blockIdx.x * 256 + threadIdx.x;
  if (j < NFLAT) atomicAdd(&counts[ef[j]], 1);
}

__global__ void scan_k(const int* __restrict__ counts, int* __restrict__ base) {
  if (threadIdx.x == 0) {
    int s = 0;
    for (int e = 0; e < NEXP; ++e) { base[e] = s; s += counts[e]; }
  }
}

__global__ void scatter_k(const int* __restrict__ ef, const int* __restrict__ base,
                          int* __restrict__ run, int* __restrict__ rowtok,
                          int* __restrict__ f2r) {
  int j = blockIdx.x * 256 + threadIdx.x;
  if (j < NFLAT) {
    int e = ef[j];
    int r = base[e] + atomicAdd(&run[e], 1);
    f2r[j] = r;
    rowtok[r] = j >> 1;
  }
}

// ---------------- grouped GEMM 1: inter = silu(x@w0) * (x@w1) ----------------
// 128m x 64n x 32k; depth-2 register sets; raw barriers (no vmcnt drain):
// per phase: LOAD(next-next) -> COMPUTE(cur) -> CVTW(next) -> lds_barrier.
__global__ __launch_bounds__(256, 3) void gemm1_k(
    const float* __restrict__ x, const float* __restrict__ w0,
    const float* __restrict__ w1, const int* __restrict__ counts,
    const int* __restrict__ base, const int* __restrict__ rowtok,
    __hip_bfloat16* __restrict__ inter) {
  int e = blockIdx.z;
  int Me = counts[e];
  int mc = blockIdx.y;
  if (mc * 128 >= Me) return;
  int rs = base[e];
  int nb = blockIdx.x * 64;
  int t = threadIdx.x;
  int wv = t >> 6, l = t & 63;
  int wr = wv >> 1, wc = wv & 1;
  int lg = l >> 4, li = l & 15;

  __shared__ __bf16 Ash[2][128 * APAD];
  __shared__ __bf16 Bsh[2][2][64 * BPAD];   // [buf][mat]

  int ra = t >> 1, kh = t & 1;              // A: row, 16-float half
  int mat = t >> 7;                          // B: which matrix this thread stages
  int n2 = (t >> 2) & 31, kq = t & 3;        // B: col-pair, k-octet
  const float* wsrc = (mat ? w1 : w0) + (size_t)e * EMBD * MLPD + nb + n2 * 2;

  int rga = mc * 128 + ra; rga = rga < Me ? rga : Me - 1;
  const float* asrc = x + (size_t)rowtok[rs + rga] * EMBD + kh * 16;

  f32x4 va[2][4];
  f32x2 vb[2][8];

  auto LOAD = [&](int s, int kk) {
    #pragma unroll
    for (int j = 0; j < 4; ++j) va[s][j] = *(const f32x4*)(asrc + kk + j * 4);
    #pragma unroll
    for (int q = 0; q < 8; ++q)
      vb[s][q] = *(const f32x2*)(wsrc + (size_t)(kk + kq * 8 + q) * MLPD);
  };
  auto CVTW = [&](int c, int s) {
    bf16x8 a0, a1;
    #pragma unroll
    for (int i = 0; i < 4; ++i) {
      a0[i] = (__bf16)va[s][0][i]; a0[4 + i] = (__bf16)va[s][1][i];
      a1[i] = (__bf16)va[s][2][i]; a1[4 + i] = (__bf16)va[s][3][i];
    }
    *(bf16x8*)(&Ash[c][ra * APAD + kh * 16])     = a0;
    *(bf16x8*)(&Ash[c][ra * APAD + kh * 16 + 8]) = a1;
    bf16x8 c0, c1;
    #pragma unroll
    for (int q = 0; q < 8; ++q) { c0[q] = (__bf16)vb[s][q][0]; c1[q] = (__bf16)vb[s][q][1]; }
    *(bf16x8*)(&Bsh[c][mat][(n2 * 2)     * BPAD + kq * 8]) = c0;
    *(bf16x8*)(&Bsh[c][mat][(n2 * 2 + 1) * BPAD + kq * 8]) = c1;
  };

  f32x4 acc0[4][2], acc1[4][2];
  #pragma unroll
  for (int i = 0; i < 4; ++i)
    #pragma unroll
    for (int j = 0; j < 2; ++j) {
      acc0[i][j] = (f32x4){0.f, 0.f, 0.f, 0.f};
      acc1[i][j] = (f32x4){0.f, 0.f, 0.f, 0.f};
    }

  auto COMPUTE = [&](int c) {
    bf16x8 af[4], bf0[2], bf1[2];
    #pragma unroll
    for (int mf = 0; mf < 4; ++mf)
      af[mf] = *(const bf16x8*)(&Ash[c][(wr * 64 + mf * 16 + li) * APAD + lg * 8]);
    #pragma unroll
    for (int nf = 0; nf < 2; ++nf) {
      bf0[nf] = *(const bf16x8*)(&Bsh[c][0][(wc * 32 + nf * 16 + li) * BPAD + lg * 8]);
      bf1[nf] = *(const bf16x8*)(&Bsh[c][1][(wc * 32 + nf * 16 + li) * BPAD + lg * 8]);
    }
    #pragma unroll
    for (int nf = 0; nf < 2; ++nf)
      #pragma unroll
      for (int mf = 0; mf < 4; ++mf) {
        acc0[mf][nf] = __builtin_amdgcn_mfma_f32_16x16x32_bf16(af[mf], bf0[nf], acc0[mf][nf], 0, 0, 0);
        acc1[mf][nf] = __builtin_amdgcn_mfma_f32_16x16x32_bf16(af[mf], bf1[nf], acc1[mf][nf], 0, 0, 0);
      }
  };

  const int NT = EMBD / BKD;  // 32 (even)
  LOAD(0, 0);
  LOAD(1, BKD);
  CVTW(0, 0);
  lds_barrier();
  for (int i = 0; i < NT; i += 2) {
    // phase A: compute buf0, stage buf1 (set1), prefetch set0 <- k(i+2)
    if (i + 2 < NT) LOAD(0, (i + 2) * BKD);
    COMPUTE(0);
    CVTW(1, 1);
    lds_barrier();
    // phase B: compute buf1, stage buf0 (set0), prefetch set1 <- k(i+3)
    if (i + 3 < NT) LOAD(1, (i + 3) * BKD);
    COMPUTE(1);
    if (i + 2 < NT) CVTW(0, 0);
    lds_barrier();
  }

  // epilogue: silu(h0)*h1 -> bf16 inter
  #pragma unroll
  for (int mf = 0; mf < 4; ++mf)
    #pragma unroll
    for (int i = 0; i < 4; ++i) {
      int rl = mc * 128 + wr * 64 + mf * 16 + lg * 4 + i;
      if (rl < Me) {
        size_t rowoff = (size_t)(rs + rl) * MLPD;
        #pragma unroll
        for (int nf = 0; nf < 2; ++nf) {
          float h0 = acc0[mf][nf][i], h1 = acc1[mf][nf][i];
          float s = h0 / (1.f + expf(-h0)) * h1;
          inter[rowoff + nb + wc * 32 + nf * 16 + li] = (__hip_bfloat16)s;
        }
      }
    }
}

// ---------------- grouped GEMM 2: out_sorted = inter @ wo ----------------
template <typename OS_T>
__global__ __launch_bounds__(256, 4) void gemm2_k(
    const __hip_bfloat16* __restrict__ inter, const float* __restrict__ wo,
    const int* __restrict__ counts, const int* __restrict__ base,
    OS_T* __restrict__ os) {
  int e = blockIdx.z;
  int Me = counts[e];
  int mc = blockIdx.y;
  if (mc * 128 >= Me) return;
  int rs = base[e];
  int nb = blockIdx.x * 64;
  int t = threadIdx.x;
  int wv = t >> 6, l = t & 63;
  int wr = wv >> 1, wc = wv & 1;
  int lg = l >> 4, li = l & 15;

  __shared__ __bf16 Ash[2][128 * APAD];
  __shared__ __bf16 Bsh[2][64 * BPAD];

  int ra = t >> 1, kh = t & 1;
  int n2 = (t >> 3) & 31, kqq = t & 7;       // B: col-pair, k-quad
  const size_t weoff = (size_t)e * MLPD * EMBD;
  const float* bsrc = wo + weoff + nb + n2 * 2;

  int rga = mc * 128 + ra; rga = rga < Me ? rga : Me - 1;
  const __hip_bfloat16* asrc = inter + (size_t)(rs + rga) * MLPD + kh * 16;

  bf16x8 va[2][2];
  f32x2 vb[2][4];

  auto LOAD = [&](int s, int kk) {
    va[s][0] = *(const bf16x8*)(asrc + kk);
    va[s][1] = *(const bf16x8*)(asrc + kk + 8);
    #pragma unroll
    for (int q = 0; q < 4; ++q)
      vb[s][q] = *(const f32x2*)(bsrc + (size_t)(kk + kqq * 4 + q) * EMBD);
  };
  auto CVTW = [&](int c, int s) {
    *(bf16x8*)(&Ash[c][ra * APAD + kh * 16])     = va[s][0];
    *(bf16x8*)(&Ash[c][ra * APAD + kh * 16 + 8]) = va[s][1];
    bf16x4 c0, c1;
    #pragma unroll
    for (int q = 0; q < 4; ++q) { c0[q] = (__bf16)vb[s][q][0]; c1[q] = (__bf16)vb[s][q][1]; }
    *(bf16x4*)(&Bsh[c][(n2 * 2)     * BPAD + kqq * 4]) = c0;
    *(bf16x4*)(&Bsh[c][(n2 * 2 + 1) * BPAD + kqq * 4]) = c1;
  };

  f32x4 acc[4][2];
  #pragma unroll
  for (int i = 0; i < 4; ++i)
    #pragma unroll
    for (int j = 0; j < 2; ++j) acc[i][j] = (f32x4){0.f, 0.f, 0.f, 0.f};

  auto COMPUTE = [&](int c) {
    bf16x8 af[4], bfr[2];
    #pragma unroll
    for (int mf = 0; mf < 4; ++mf)
      af[mf] = *(const bf16x8*)(&Ash[c][(wr * 64 + mf * 16 + li) * APAD + lg * 8]);
    #pragma unroll
    for (int nf = 0; nf < 2; ++nf)
      bfr[nf] = *(const bf16x8*)(&Bsh[c][(wc * 32 + nf * 16 + li) * BPAD + lg * 8]);
    #pragma unroll
    for (int nf = 0; nf < 2; ++nf)
      #pragma unroll
      for (int mf = 0; mf < 4; ++mf)
        acc[mf][nf] = __builtin_amdgcn_mfma_f32_16x16x32_bf16(af[mf], bfr[nf], acc[mf][nf], 0, 0, 0);
  };

  const int NT = MLPD / BKD;  // 64 (even)
  LOAD(0, 0);
  LOAD(1, BKD);
  CVTW(0, 0);
  lds_barrier();
  for (int i = 0; i < NT; i += 2) {
    if (i + 2 < NT) LOAD(0, (i + 2) * BKD);
    COMPUTE(0);
    CVTW(1, 1);
    lds_barrier();
    if (i + 3 < NT) LOAD(1, (i + 3) * BKD);
    COMPUTE(1);
    if (i + 2 < NT) CVTW(0, 0);
    lds_barrier();
  }

  #pragma unroll
  for (int mf = 0; mf < 4; ++mf)
    #pragma unroll
    for (int i = 0; i < 4; ++i) {
      int rl = mc * 128 + wr * 64 + mf * 16 + lg * 4 + i;
      if (rl < Me) {
        size_t rowoff = (size_t)(rs + rl) * EMBD;
        #pragma unroll
        for (int nf = 0; nf < 2; ++nf)
          os[rowoff + nb + wc * 32 + nf * 16 + li] = (OS_T)acc[mf][nf][i];
      }
    }
}

// ---------------- combine: out[t] = w1*os[r1] + w2*os[r2] ----------------
template <typename OS_T>
__global__ __launch_bounds__(256) void combine_k(
    const OS_T* __restrict__ os, const int* __restrict__ f2r,
    const float* __restrict__ wf, float* __restrict__ out) {
  int t = blockIdx.x;
  int c = threadIdx.x * 4;
  int r0 = f2r[2 * t], r1 = f2r[2 * t + 1];
  float wa = wf[2 * t], wb = wf[2 * t + 1];
  const OS_T* pa = os + (size_t)r0 * EMBD + c;
  const OS_T* pb = os + (size_t)r1 * EMBD + c;
  float4 o;
  o.x = wa * (float)pa[0] + wb * (float)pb[0];
  o.y = wa * (float)pa[1] + wb * (float)pb[1];
  o.z = wa * (float)pa[2] + wb * (float)pb[2];
  o.w = wa * (float)pa[3] + wb * (float)pb[3];
  *(float4*)(out + (size_t)t * EMBD + c) = o;
}

// ---------------- launcher ----------------
extern "C" void kernel_launch(void* const* d_in, const int* in_sizes, int n_in,
                              void* d_out, int out_size, void* d_ws, size_t ws_size,
                              hipStream_t stream) {
  const float* x  = (const float*)d_in[0];
  const float* gk = (const float*)d_in[1];
  const float* w0 = (const float*)d_in[2];
  const float* w1 = (const float*)d_in[3];
  const float* wo = (const float*)d_in[4];
  float* out = (float*)d_out;
  char* ws = (char*)d_ws;

  int*   counts = (int*)(ws + OFF_COUNTS);
  int*   basep  = (int*)(ws + OFF_BASE);
  int*   run    = (int*)(ws + OFF_RUN);
  int*   ef     = (int*)(ws + OFF_EFLAT);
  float* wfl    = (float*)(ws + OFF_WFLAT);
  int*   rowtok = (int*)(ws + OFF_ROWTOK);
  int*   f2r    = (int*)(ws + OFF_F2R);
  __hip_bfloat16* inter = (__hip_bfloat16*)(ws + OFF_INTER);

  hipMemsetAsync(ws, 0, 1024, stream);
  router_topk<<<NTOK / 4, 256, 0, stream>>>(x, gk, ef, wfl);
  hist_k<<<NFLAT / 256, 256, 0, stream>>>(ef, counts);
  scan_k<<<1, 64, 0, stream>>>(counts, basep);
  scatter_k<<<NFLAT / 256, 256, 0, stream>>>(ef, basep, run, rowtok, f2r);
  gemm1_k<<<dim3(MLPD / 64, MAXCH, NEXP), 256, 0, stream>>>(x, w0, w1, counts, basep, rowtok, inter);

  if (ws_size >= NEED_F32) {
    float* os = (float*)(ws + OFF_OS);
    gemm2_k<float><<<dim3(EMBD / 64, MAXCH, NEXP), 256, 0, stream>>>(inter, wo, counts, basep, os);
    combine_k<float><<<NTOK, 256, 0, stream>>>(os, f2r, wfl, out);
  } else {
    __hip_bfloat16* os = (__hip_bfloat16*)(ws + OFF_OS);
    gemm2_k<__hip_bfloat16><<<dim3(EMBD / 64, MAXCH, NEXP), 256, 0, stream>>>(inter, wo, counts, basep, os);
    combine_k<__hip_bfloat16><<<NTOK, 256, 0, stream>>>(os, f2r, wfl, out);
  }
}

// Round 7
// 1097.949 us; speedup vs baseline: 1.3320x; 1.3320x over previous
//
#include <hip/hip_runtime.h>
#include <hip/hip_bf16.h>
#include <math.h>

#define NTOK   8192      // B*S tokens
#define NEXP   64
#define EMBD   1024
#define MLPD   2048
#define TOPK   2
#define NFLAT  (NTOK * TOPK)
#define BKD    32        // K tile
#define MAXCH  8         // max m-chunks of 128 (mean Me=256)

typedef __attribute__((ext_vector_type(4)))  float  f32x4;
typedef __attribute__((ext_vector_type(16))) float  f32x16;
typedef __attribute__((ext_vector_type(8)))  __bf16 bf16x8;

// global -> LDS direct (16B/lane). LDS dest = wave-uniform base + lane*16.
__device__ __forceinline__ void gl16(const void* g, void* lds_base) {
  __builtin_amdgcn_global_load_lds(
      (const __attribute__((address_space(1))) unsigned int*)g,
      (__attribute__((address_space(3))) unsigned int*)lds_base, 16, 0, 0);
}
// wait all my gl_lds done, then join (stage visible to all)
__device__ __forceinline__ void vm0_bar() {
  asm volatile("s_waitcnt vmcnt(0)" ::: "memory");
  __builtin_amdgcn_s_barrier();
}
// wait my LDS reads done, then join (safe to overwrite LDS)
__device__ __forceinline__ void lgkm0_bar() {
  asm volatile("s_waitcnt lgkmcnt(0)" ::: "memory");
  __builtin_amdgcn_sched_barrier(0);
  __builtin_amdgcn_s_barrier();
}

// ---------------- workspace layout (bytes) ----------------
#define OFF_COUNTS 0
#define OFF_BASE   256
#define OFF_RUN    512
#define OFF_EFLAT  1024
#define OFF_WFLAT  (1024 + 65536)
#define OFF_ROWTOK (1024 + 2 * 65536)
#define OFF_F2R    (1024 + 3 * 65536)
#define OFF_INTER  (1024 + 4 * 65536)                       // bf16 [16384][2048]
#define OFF_OS     (OFF_INTER + (size_t)NFLAT * MLPD * 2)   // out_sorted
#define NEED_F32   (OFF_OS + (size_t)NFLAT * EMBD * 4)

// ---------------- router: logits + top-2 + softmax ----------------
__global__ __launch_bounds__(256) void router_topk(
    const float* __restrict__ x, const float* __restrict__ gk,
    int* __restrict__ e_flat, float* __restrict__ w_flat) {
  int t = blockIdx.x * 4 + (threadIdx.x >> 6);
  int l = threadIdx.x & 63;
  const float* xr = x + (size_t)t * EMBD;
  float acc = 0.f;
  #pragma unroll 8
  for (int i = 0; i < EMBD; ++i)
    acc = fmaf(xr[i], gk[i * NEXP + l], acc);
  float m = acc;
  for (int o = 32; o; o >>= 1) m = fmaxf(m, __shfl_xor(m, o));
  unsigned long long b1 = __ballot(acc == m);
  int i1 = __ffsll(b1) - 1;
  float v2 = (l == i1) ? -INFINITY : acc;
  float m2 = v2;
  for (int o = 32; o; o >>= 1) m2 = fmaxf(m2, __shfl_xor(m2, o));
  unsigned long long b2 = __ballot(v2 == m2);
  int i2 = __ffsll(b2) - 1;
  if (l == 0) {
    float e2 = expf(m2 - m);
    float inv = 1.f / (1.f + e2);
    e_flat[2 * t] = i1;  e_flat[2 * t + 1] = i2;
    w_flat[2 * t] = inv; w_flat[2 * t + 1] = e2 * inv;
  }
}

// ---------------- histogram / scan / scatter ----------------
__global__ void hist_k(const int* __restrict__ ef, int* __restrict__ counts) {
  int j = blockIdx.x * 256 + threadIdx.x;
  if (j < NFLAT) atomicAdd(&counts[ef[j]], 1);
}

__global__ void scan_k(const int* __restrict__ counts, int* __restrict__ base) {
  if (threadIdx.x == 0) {
    int s = 0;
    for (int e = 0; e < NEXP; ++e) { base[e] = s; s += counts[e]; }
  }
}

__global__ void scatter_k(const int* __restrict__ ef, const int* __restrict__ base,
                          int* __restrict__ run, int* __restrict__ rowtok,
                          int* __restrict__ f2r) {
  int j = blockIdx.x * 256 + threadIdx.x;
  if (j < NFLAT) {
    int e = ef[j];
    int r = base[e] + atomicAdd(&run[e], 1);
    f2r[j] = r;
    rowtok[r] = j >> 1;
  }
}

// ---------------- grouped GEMM 1: inter = silu(x@w0) * (x@w1) ----------------
// 128m x 64n x 32k; 4 waves 2x2 (wave = 64m x 32n); MFMA 32x32x16.
// ALL staging via global_load_lds (f32 stays f32 into LDS; cvt on read).
// A LDS fragment-major: [slot=g*4+h][lane][4f] (1KB/instr, per-lane swizzled
// global source). B LDS [k32][n64] f32; column read = ds_read_b32, bank=lane&31
// -> 2-way (free). Single buffer, 2-barrier loop; stage(ks+1) issued before
// MFMA so loads fly under compute + cross-block overlap.
__global__ __launch_bounds__(256, 3) void gemm1_k(
    const float* __restrict__ x, const float* __restrict__ w0,
    const float* __restrict__ w1, const int* __restrict__ counts,
    const int* __restrict__ base, const int* __restrict__ rowtok,
    __hip_bfloat16* __restrict__ inter) {
  int e = blockIdx.z;
  int Me = counts[e];
  int mc = blockIdx.y;
  if (mc * 128 >= Me) return;
  int rs = base[e];
  int nb = blockIdx.x * 64;
  int t = threadIdx.x;
  int wv = t >> 6, l = t & 63;
  int wr = wv >> 1, wc = wv & 1;
  int lo = l & 31, hi = l >> 5;

  __shared__ float Ash[4096];        // 16KB  [slot16][lane64][4f]
  __shared__ float Bsh[2 * 2048];    // 16KB  [mat][k32][n64]

  // --- staging precompute (wave-specialized) ---
  const float* abase0 = x;  // wv0/wv1: A rows (fragment-major source)
  const float* abase1 = x;
  const float* wbase  = w0; // wv2/wv3: B mat rows
  if (wv < 2) {
    int g0 = wv * 2, g1 = wv * 2 + 1;
    int r0 = mc * 128 + g0 * 32 + lo; r0 = r0 < Me ? r0 : Me - 1;
    int r1 = mc * 128 + g1 * 32 + lo; r1 = r1 < Me ? r1 : Me - 1;
    abase0 = x + (size_t)rowtok[rs + r0] * EMBD + hi * 4;
    abase1 = x + (size_t)rowtok[rs + r1] * EMBD + hi * 4;
  } else {
    const float* w = (wv == 3) ? w1 : w0;
    wbase = w + (size_t)e * EMBD * MLPD + nb + (l & 15) * 4 + (size_t)(l >> 4) * MLPD;
  }
  int matofs = (wv & 1) * 2048;

  auto STAGE = [&](int kk) {
    if (wv < 2) {
      #pragma unroll
      for (int h = 0; h < 4; ++h) {
        gl16(abase0 + kk + h * 8, &Ash[((wv * 2 + 0) * 4 + h) * 256]);
        gl16(abase1 + kk + h * 8, &Ash[((wv * 2 + 1) * 4 + h) * 256]);
      }
    } else {
      #pragma unroll
      for (int j = 0; j < 8; ++j)
        gl16(wbase + (size_t)(kk + j * 4) * MLPD, &Bsh[matofs + j * 256]);
    }
  };

  f32x16 acc0[2], acc1[2];
  #pragma unroll
  for (int g = 0; g < 2; ++g)
    #pragma unroll
    for (int r = 0; r < 16; ++r) { acc0[g][r] = 0.f; acc1[g][r] = 0.f; }

  STAGE(0);
  const int NT = EMBD / BKD;  // 32
  for (int ks = 0; ks < NT; ++ks) {
    vm0_bar();                      // stage(ks) landed (each wave waits its own)
    // A frags: (g,kh) -> 8 k-floats = 2 x b128 at +0/+512B
    f32x4 a[2][2][2];
    #pragma unroll
    for (int g = 0; g < 2; ++g)
      #pragma unroll
      for (int kh = 0; kh < 2; ++kh) {
        int idx = (((wr * 2 + g) * 4 + kh * 2 + hi) * 256) + lo * 4;
        a[g][kh][0] = *(const f32x4*)&Ash[idx];
        a[g][kh][1] = *(const f32x4*)&Ash[idx + 128];
      }
    // B frags: (mat,kh) -> 8 strided f32 (bank = lo, 2-way free)
    float b[2][2][8];
    #pragma unroll
    for (int m = 0; m < 2; ++m)
      #pragma unroll
      for (int kh = 0; kh < 2; ++kh) {
        int bi = m * 2048 + (kh * 16 + hi * 8) * 64 + wc * 32 + lo;
        #pragma unroll
        for (int q = 0; q < 8; ++q) b[m][kh][q] = Bsh[bi + q * 64];
      }
    lgkm0_bar();                    // all waves done reading LDS
    if (ks + 1 < NT) STAGE((ks + 1) * BKD);   // overwrite ok; flies under MFMA
    // cvt + MFMA
    bf16x8 av[2][2], bv[2][2];
    #pragma unroll
    for (int g = 0; g < 2; ++g)
      #pragma unroll
      for (int kh = 0; kh < 2; ++kh) {
        #pragma unroll
        for (int q = 0; q < 4; ++q) {
          av[g][kh][q]     = (__bf16)a[g][kh][0][q];
          av[g][kh][4 + q] = (__bf16)a[g][kh][1][q];
        }
      }
    #pragma unroll
    for (int m = 0; m < 2; ++m)
      #pragma unroll
      for (int kh = 0; kh < 2; ++kh)
        #pragma unroll
        for (int q = 0; q < 8; ++q) bv[m][kh][q] = (__bf16)b[m][kh][q];
    #pragma unroll
    for (int kh = 0; kh < 2; ++kh)
      #pragma unroll
      for (int g = 0; g < 2; ++g) {
        acc0[g] = __builtin_amdgcn_mfma_f32_32x32x16_bf16(av[g][kh], bv[0][kh], acc0[g], 0, 0, 0);
        acc1[g] = __builtin_amdgcn_mfma_f32_32x32x16_bf16(av[g][kh], bv[1][kh], acc1[g], 0, 0, 0);
      }
  }

  // epilogue: silu(h0)*h1 -> bf16 inter. 32x32 C map: col=lo, row=(r&3)+8*(r>>2)+4*hi
  #pragma unroll
  for (int g = 0; g < 2; ++g)
    #pragma unroll
    for (int r = 0; r < 16; ++r) {
      int rl = mc * 128 + wr * 64 + g * 32 + (r & 3) + 8 * (r >> 2) + 4 * hi;
      if (rl < Me) {
        float h0 = acc0[g][r], h1 = acc1[g][r];
        float s = h0 / (1.f + expf(-h0)) * h1;
        inter[(size_t)(rs + rl) * MLPD + nb + wc * 32 + lo] = (__hip_bfloat16)s;
      }
    }
}

// ---------------- grouped GEMM 2: out_sorted = inter @ wo ----------------
// Same structure; A = bf16 inter, fragment-major 16B/lane (1 b128 per frag).
template <typename OS_T>
__global__ __launch_bounds__(256, 4) void gemm2_k(
    const __hip_bfloat16* __restrict__ inter, const float* __restrict__ wo,
    const int* __restrict__ counts, const int* __restrict__ base,
    OS_T* __restrict__ os) {
  int e = blockIdx.z;
  int Me = counts[e];
  int mc = blockIdx.y;
  if (mc * 128 >= Me) return;
  int rs = base[e];
  int nb = blockIdx.x * 64;
  int t = threadIdx.x;
  int wv = t >> 6, l = t & 63;
  int wr = wv >> 1, wc = wv & 1;
  int lo = l & 31, hi = l >> 5;

  __shared__ __bf16 A2[4096];       // 8KB  [slot=g*2+kh][lane][8bf16]
  __shared__ float  B2[2048];       // 8KB  [k32][n64]

  const __hip_bfloat16* ab0 = inter;
  const __hip_bfloat16* ab1 = inter;
  const float* wbase = wo;
  if (wv < 2) {
    int g0 = wv * 2, g1 = wv * 2 + 1;
    int r0 = mc * 128 + g0 * 32 + lo; r0 = r0 < Me ? r0 : Me - 1;
    int r1 = mc * 128 + g1 * 32 + lo; r1 = r1 < Me ? r1 : Me - 1;
    ab0 = inter + (size_t)(rs + r0) * MLPD + hi * 8;
    ab1 = inter + (size_t)(rs + r1) * MLPD + hi * 8;
  } else {
    wbase = wo + (size_t)e * MLPD * EMBD + nb + (l & 15) * 4 + (size_t)(l >> 4) * EMBD;
  }
  int jofs = (wv & 1) * 4;          // wv2: j 0..3, wv3: j 4..7

  auto STAGE = [&](int kk) {
    if (wv < 2) {
      #pragma unroll
      for (int kh = 0; kh < 2; ++kh) {
        gl16(ab0 + kk + kh * 16, &A2[((wv * 2 + 0) * 2 + kh) * 512]);
        gl16(ab1 + kk + kh * 16, &A2[((wv * 2 + 1) * 2 + kh) * 512]);
      }
    } else {
      #pragma unroll
      for (int j = 0; j < 4; ++j)
        gl16(wbase + (size_t)(kk + (jofs + j) * 4) * EMBD, &B2[(jofs + j) * 256]);
    }
  };

  f32x16 acc[2];
  #pragma unroll
  for (int g = 0; g < 2; ++g)
    #pragma unroll
    for (int r = 0; r < 16; ++r) acc[g][r] = 0.f;

  STAGE(0);
  const int NT = MLPD / BKD;  // 64
  for (int ks = 0; ks < NT; ++ks) {
    vm0_bar();
    bf16x8 av[2][2];
    #pragma unroll
    for (int g = 0; g < 2; ++g)
      #pragma unroll
      for (int kh = 0; kh < 2; ++kh)
        av[g][kh] = *(const bf16x8*)&A2[(((wr * 2 + g) * 2 + kh) * 512) + l * 8];
    float b[2][8];
    #pragma unroll
    for (int kh = 0; kh < 2; ++kh) {
      int bi = (kh * 16 + hi * 8) * 64 + wc * 32 + lo;
      #pragma unroll
      for (int q = 0; q < 8; ++q) b[kh][q] = B2[bi + q * 64];
    }
    lgkm0_bar();
    if (ks + 1 < NT) STAGE((ks + 1) * BKD);
    bf16x8 bv[2];
    #pragma unroll
    for (int kh = 0; kh < 2; ++kh)
      #pragma unroll
      for (int q = 0; q < 8; ++q) bv[kh][q] = (__bf16)b[kh][q];
    #pragma unroll
    for (int kh = 0; kh < 2; ++kh)
      #pragma unroll
      for (int g = 0; g < 2; ++g)
        acc[g] = __builtin_amdgcn_mfma_f32_32x32x16_bf16(av[g][kh], bv[kh], acc[g], 0, 0, 0);
  }

  #pragma unroll
  for (int g = 0; g < 2; ++g)
    #pragma unroll
    for (int r = 0; r < 16; ++r) {
      int rl = mc * 128 + wr * 64 + g * 32 + (r & 3) + 8 * (r >> 2) + 4 * hi;
      if (rl < Me)
        os[(size_t)(rs + rl) * EMBD + nb + wc * 32 + lo] = (OS_T)acc[g][r];
    }
}

// ---------------- combine: out[t] = w1*os[r1] + w2*os[r2] ----------------
template <typename OS_T>
__global__ __launch_bounds__(256) void combine_k(
    const OS_T* __restrict__ os, const int* __restrict__ f2r,
    const float* __restrict__ wf, float* __restrict__ out) {
  int t = blockIdx.x;
  int c = threadIdx.x * 4;
  int r0 = f2r[2 * t], r1 = f2r[2 * t + 1];
  float wa = wf[2 * t], wb = wf[2 * t + 1];
  const OS_T* pa = os + (size_t)r0 * EMBD + c;
  const OS_T* pb = os + (size_t)r1 * EMBD + c;
  float4 o;
  o.x = wa * (float)pa[0] + wb * (float)pb[0];
  o.y = wa * (float)pa[1] + wb * (float)pb[1];
  o.z = wa * (float)pa[2] + wb * (float)pb[2];
  o.w = wa * (float)pa[3] + wb * (float)pb[3];
  *(float4*)(out + (size_t)t * EMBD + c) = o;
}

// ---------------- launcher ----------------
extern "C" void kernel_launch(void* const* d_in, const int* in_sizes, int n_in,
                              void* d_out, int out_size, void* d_ws, size_t ws_size,
                              hipStream_t stream) {
  const float* x  = (const float*)d_in[0];
  const float* gk = (const float*)d_in[1];
  const float* w0 = (const float*)d_in[2];
  const float* w1 = (const float*)d_in[3];
  const float* wo = (const float*)d_in[4];
  float* out = (float*)d_out;
  char* ws = (char*)d_ws;

  int*   counts = (int*)(ws + OFF_COUNTS);
  int*   basep  = (int*)(ws + OFF_BASE);
  int*   run    = (int*)(ws + OFF_RUN);
  int*   ef     = (int*)(ws + OFF_EFLAT);
  float* wfl    = (float*)(ws + OFF_WFLAT);
  int*   rowtok = (int*)(ws + OFF_ROWTOK);
  int*   f2r    = (int*)(ws + OFF_F2R);
  __hip_bfloat16* inter = (__hip_bfloat16*)(ws + OFF_INTER);

  hipMemsetAsync(ws, 0, 1024, stream);
  router_topk<<<NTOK / 4, 256, 0, stream>>>(x, gk, ef, wfl);
  hist_k<<<NFLAT / 256, 256, 0, stream>>>(ef, counts);
  scan_k<<<1, 64, 0, stream>>>(counts, basep);
  scatter_k<<<NFLAT / 256, 256, 0, stream>>>(ef, basep, run, rowtok, f2r);
  gemm1_k<<<dim3(MLPD / 64, MAXCH, NEXP), 256, 0, stream>>>(x, w0, w1, counts, basep, rowtok, inter);

  if (ws_size >= NEED_F32) {
    float* os = (float*)(ws + OFF_OS);
    gemm2_k<float><<<dim3(EMBD / 64, MAXCH, NEXP), 256, 0, stream>>>(inter, wo, counts, basep, os);
    combine_k<float><<<NTOK, 256, 0, stream>>>(os, f2r, wfl, out);
  } else {
    __hip_bfloat16* os = (__hip_bfloat16*)(ws + OFF_OS);
    gemm2_k<__hip_bfloat16><<<dim3(EMBD / 64, MAXCH, NEXP), 256, 0, stream>>>(inter, wo, counts, basep, os);
    combine_k<__hip_bfloat16><<<NTOK, 256, 0, stream>>>(os, f2r, wfl, out);
  }
}

// Round 8
// 1087.019 us; speedup vs baseline: 1.3454x; 1.0101x over previous
//
#include <hip/hip_runtime.h>
#include <hip/hip_bf16.h>
#include <math.h>

#define NTOK   8192      // B*S tokens
#define NEXP   64
#define EMBD   1024
#define MLPD   2048
#define TOPK   2
#define NFLAT  (NTOK * TOPK)
#define BKD    32        // K tile
#define MAXCH  8         // max m-chunks of 128 (mean Me=256)

typedef __attribute__((ext_vector_type(4)))  float  f32x4;
typedef __attribute__((ext_vector_type(16))) float  f32x16;
typedef __attribute__((ext_vector_type(8)))  __bf16 bf16x8;

// global -> LDS direct (16B/lane). LDS dest = wave-uniform base + lane*16.
__device__ __forceinline__ void gl16(const void* g, void* lds_base) {
  __builtin_amdgcn_global_load_lds(
      (const __attribute__((address_space(1))) unsigned int*)g,
      (__attribute__((address_space(3))) unsigned int*)lds_base, 16, 0, 0);
}
__device__ __forceinline__ void lgkm0_bar() {
  asm volatile("s_waitcnt lgkmcnt(0)" ::: "memory");
  __builtin_amdgcn_sched_barrier(0);
  __builtin_amdgcn_s_barrier();
}

// ---------------- workspace layout (bytes) ----------------
#define OFF_COUNTS 0
#define OFF_BASE   256
#define OFF_RUN    512
#define OFF_EFLAT  1024
#define OFF_WFLAT  (1024 + 65536)
#define OFF_ROWTOK (1024 + 2 * 65536)
#define OFF_F2R    (1024 + 3 * 65536)
#define OFF_INTER  (1024 + 4 * 65536)                       // bf16 [16384][2048]
#define OFF_OS     (OFF_INTER + (size_t)NFLAT * MLPD * 2)   // out_sorted
#define NEED_F32   (OFF_OS + (size_t)NFLAT * EMBD * 4)

// ---------------- router: logits + top-2 + softmax ----------------
__global__ __launch_bounds__(256) void router_topk(
    const float* __restrict__ x, const float* __restrict__ gk,
    int* __restrict__ e_flat, float* __restrict__ w_flat) {
  int t = blockIdx.x * 4 + (threadIdx.x >> 6);
  int l = threadIdx.x & 63;
  const float* xr = x + (size_t)t * EMBD;
  float acc = 0.f;
  #pragma unroll 8
  for (int i = 0; i < EMBD; ++i)
    acc = fmaf(xr[i], gk[i * NEXP + l], acc);
  float m = acc;
  for (int o = 32; o; o >>= 1) m = fmaxf(m, __shfl_xor(m, o));
  unsigned long long b1 = __ballot(acc == m);
  int i1 = __ffsll(b1) - 1;
  float v2 = (l == i1) ? -INFINITY : acc;
  float m2 = v2;
  for (int o = 32; o; o >>= 1) m2 = fmaxf(m2, __shfl_xor(m2, o));
  unsigned long long b2 = __ballot(v2 == m2);
  int i2 = __ffsll(b2) - 1;
  if (l == 0) {
    float e2 = expf(m2 - m);
    float inv = 1.f / (1.f + e2);
    e_flat[2 * t] = i1;  e_flat[2 * t + 1] = i2;
    w_flat[2 * t] = inv; w_flat[2 * t + 1] = e2 * inv;
  }
}

// ---------------- histogram / scan / scatter ----------------
__global__ void hist_k(const int* __restrict__ ef, int* __restrict__ counts) {
  int j = blockIdx.x * 256 + threadIdx.x;
  if (j < NFLAT) atomicAdd(&counts[ef[j]], 1);
}

__global__ void scan_k(const int* __restrict__ counts, int* __restrict__ base) {
  if (threadIdx.x == 0) {
    int s = 0;
    for (int e = 0; e < NEXP; ++e) { base[e] = s; s += counts[e]; }
  }
}

__global__ void scatter_k(const int* __restrict__ ef, const int* __restrict__ base,
                          int* __restrict__ run, int* __restrict__ rowtok,
                          int* __restrict__ f2r) {
  int j = blockIdx.x * 256 + threadIdx.x;
  if (j < NFLAT) {
    int e = ef[j];
    int r = base[e] + atomicAdd(&run[e], 1);
    f2r[j] = r;
    rowtok[r] = j >> 1;
  }
}

// ---------------- grouped GEMM 1: inter = silu(x@w0) * (x@w1) ----------------
// 128m x 64n x 32k; 4 waves 2x2 (wave = 64m x 32n); MFMA 32x32x16.
// Staging via global_load_lds, wave-specialized: wv0/1 stage A (single buffer,
// x is L2-warm), wv2/3 stage B (DOUBLE buffer + counted vmcnt(8): stage(ks+1)
// stays in flight across the barrier; waited one full iteration later).
__global__ __launch_bounds__(256, 3) void gemm1_k(
    const float* __restrict__ x, const float* __restrict__ w0,
    const float* __restrict__ w1, const int* __restrict__ counts,
    const int* __restrict__ base, const int* __restrict__ rowtok,
    __hip_bfloat16* __restrict__ inter) {
  int e = blockIdx.z;
  int Me = counts[e];
  int mc = blockIdx.y;
  if (mc * 128 >= Me) return;
  int rs = base[e];
  int nb = blockIdx.x * 64;
  int t = threadIdx.x;
  int wv = t >> 6, l = t & 63;
  int wr = wv >> 1, wc = wv & 1;
  int lo = l & 31, hi = l >> 5;

  __shared__ float Ash[4096];        // 16KB [slot16][lane64][4f]
  __shared__ float Bsh[2][4096];     // 32KB [buf][mat][k32][n64]

  const float* abase0 = x;
  const float* abase1 = x;
  const float* wbase  = w0;
  if (wv < 2) {
    int g0 = wv * 2, g1 = wv * 2 + 1;
    int r0 = mc * 128 + g0 * 32 + lo; r0 = r0 < Me ? r0 : Me - 1;
    int r1 = mc * 128 + g1 * 32 + lo; r1 = r1 < Me ? r1 : Me - 1;
    abase0 = x + (size_t)rowtok[rs + r0] * EMBD + hi * 4;
    abase1 = x + (size_t)rowtok[rs + r1] * EMBD + hi * 4;
  } else {
    const float* w = (wv == 3) ? w1 : w0;
    wbase = w + (size_t)e * EMBD * MLPD + nb + (l & 15) * 4 + (size_t)(l >> 4) * MLPD;
  }
  int matofs = (wv & 1) * 2048;

  auto STAGE_A = [&](int kk) {
    #pragma unroll
    for (int h = 0; h < 4; ++h) {
      gl16(abase0 + kk + h * 8, &Ash[((wv * 2 + 0) * 4 + h) * 256]);
      gl16(abase1 + kk + h * 8, &Ash[((wv * 2 + 1) * 4 + h) * 256]);
    }
  };
  auto STAGE_B = [&](int buf, int kk) {
    #pragma unroll
    for (int j = 0; j < 8; ++j)
      gl16(wbase + (size_t)(kk + j * 4) * MLPD, &Bsh[buf][matofs + j * 256]);
  };

  f32x16 acc0[2], acc1[2];
  #pragma unroll
  for (int g = 0; g < 2; ++g)
    #pragma unroll
    for (int r = 0; r < 16; ++r) { acc0[g][r] = 0.f; acc1[g][r] = 0.f; }

  if (wv < 2) STAGE_A(0);
  else { STAGE_B(0, 0); STAGE_B(1, BKD); }

  const int NT = EMBD / BKD;  // 32
  for (int ks = 0; ks < NT; ++ks) {
    // A waves: drain own 8 loads. B waves: counted wait — stage(ks) done,
    // stage(ks+1)'s 8 loads stay in flight across the barrier.
    if (wv >= 2 && ks + 1 < NT) asm volatile("s_waitcnt vmcnt(8)" ::: "memory");
    else                        asm volatile("s_waitcnt vmcnt(0)" ::: "memory");
    __builtin_amdgcn_s_barrier();

    f32x4 a[2][2][2];
    #pragma unroll
    for (int g = 0; g < 2; ++g)
      #pragma unroll
      for (int kh = 0; kh < 2; ++kh) {
        int idx = (((wr * 2 + g) * 4 + kh * 2 + hi) * 256) + lo * 4;
        a[g][kh][0] = *(const f32x4*)&Ash[idx];
        a[g][kh][1] = *(const f32x4*)&Ash[idx + 128];
      }
    float b[2][2][8];
    const float* bb = Bsh[ks & 1];
    #pragma unroll
    for (int m = 0; m < 2; ++m)
      #pragma unroll
      for (int kh = 0; kh < 2; ++kh) {
        int bi = m * 2048 + (kh * 16 + hi * 8) * 64 + wc * 32 + lo;
        #pragma unroll
        for (int q = 0; q < 8; ++q) b[m][kh][q] = bb[bi + q * 64];
      }
    lgkm0_bar();                    // all waves done reading LDS
    if (wv < 2) { if (ks + 1 < NT) STAGE_A((ks + 1) * BKD); }
    else if (ks + 2 < NT) STAGE_B(ks & 1, (ks + 2) * BKD);

    bf16x8 av[2][2], bv[2][2];
    #pragma unroll
    for (int g = 0; g < 2; ++g)
      #pragma unroll
      for (int kh = 0; kh < 2; ++kh)
        #pragma unroll
        for (int q = 0; q < 4; ++q) {
          av[g][kh][q]     = (__bf16)a[g][kh][0][q];
          av[g][kh][4 + q] = (__bf16)a[g][kh][1][q];
        }
    #pragma unroll
    for (int m = 0; m < 2; ++m)
      #pragma unroll
      for (int kh = 0; kh < 2; ++kh)
        #pragma unroll
        for (int q = 0; q < 8; ++q) bv[m][kh][q] = (__bf16)b[m][kh][q];
    #pragma unroll
    for (int kh = 0; kh < 2; ++kh)
      #pragma unroll
      for (int g = 0; g < 2; ++g) {
        acc0[g] = __builtin_amdgcn_mfma_f32_32x32x16_bf16(av[g][kh], bv[0][kh], acc0[g], 0, 0, 0);
        acc1[g] = __builtin_amdgcn_mfma_f32_32x32x16_bf16(av[g][kh], bv[1][kh], acc1[g], 0, 0, 0);
      }
  }

  // epilogue: silu(h0)*h1 -> bf16 inter. 32x32 C map: col=lo, row=(r&3)+8*(r>>2)+4*hi
  #pragma unroll
  for (int g = 0; g < 2; ++g)
    #pragma unroll
    for (int r = 0; r < 16; ++r) {
      int rl = mc * 128 + wr * 64 + g * 32 + (r & 3) + 8 * (r >> 2) + 4 * hi;
      if (rl < Me) {
        float h0 = acc0[g][r], h1 = acc1[g][r];
        float s = h0 / (1.f + expf(-h0)) * h1;
        inter[(size_t)(rs + rl) * MLPD + nb + wc * 32 + lo] = (__hip_bfloat16)s;
      }
    }
}

// ---------------- grouped GEMM 2: out_sorted = inter @ wo ----------------
// Both operands double-buffered; counted vmcnt(4).
template <typename OS_T>
__global__ __launch_bounds__(256, 4) void gemm2_k(
    const __hip_bfloat16* __restrict__ inter, const float* __restrict__ wo,
    const int* __restrict__ counts, const int* __restrict__ base,
    OS_T* __restrict__ os) {
  int e = blockIdx.z;
  int Me = counts[e];
  int mc = blockIdx.y;
  if (mc * 128 >= Me) return;
  int rs = base[e];
  int nb = blockIdx.x * 64;
  int t = threadIdx.x;
  int wv = t >> 6, l = t & 63;
  int wr = wv >> 1, wc = wv & 1;
  int lo = l & 31, hi = l >> 5;

  __shared__ __bf16 A2[2][4096];    // 16KB [buf][slot=g*2+kh][lane][8bf16]
  __shared__ float  B2[2][2048];    // 16KB [buf][k32][n64]

  const __hip_bfloat16* ab0 = inter;
  const __hip_bfloat16* ab1 = inter;
  const float* wbase = wo;
  if (wv < 2) {
    int g0 = wv * 2, g1 = wv * 2 + 1;
    int r0 = mc * 128 + g0 * 32 + lo; r0 = r0 < Me ? r0 : Me - 1;
    int r1 = mc * 128 + g1 * 32 + lo; r1 = r1 < Me ? r1 : Me - 1;
    ab0 = inter + (size_t)(rs + r0) * MLPD + hi * 8;
    ab1 = inter + (size_t)(rs + r1) * MLPD + hi * 8;
  } else {
    wbase = wo + (size_t)e * MLPD * EMBD + nb + (l & 15) * 4 + (size_t)(l >> 4) * EMBD;
  }
  int jofs = (wv & 1) * 4;          // wv2: j 0..3, wv3: j 4..7

  auto STAGE = [&](int buf, int kk) {
    if (wv < 2) {
      #pragma unroll
      for (int kh = 0; kh < 2; ++kh) {
        gl16(ab0 + kk + kh * 16, &A2[buf][((wv * 2 + 0) * 2 + kh) * 512]);
        gl16(ab1 + kk + kh * 16, &A2[buf][((wv * 2 + 1) * 2 + kh) * 512]);
      }
    } else {
      #pragma unroll
      for (int j = 0; j < 4; ++j)
        gl16(wbase + (size_t)(kk + (jofs + j) * 4) * EMBD, &B2[buf][(jofs + j) * 256]);
    }
  };

  f32x16 acc[2];
  #pragma unroll
  for (int g = 0; g < 2; ++g)
    #pragma unroll
    for (int r = 0; r < 16; ++r) acc[g][r] = 0.f;

  STAGE(0, 0);
  STAGE(1, BKD);
  const int NT = MLPD / BKD;  // 64
  for (int ks = 0; ks < NT; ++ks) {
    if (ks + 1 < NT) asm volatile("s_waitcnt vmcnt(4)" ::: "memory");
    else             asm volatile("s_waitcnt vmcnt(0)" ::: "memory");
    __builtin_amdgcn_s_barrier();

    bf16x8 av[2][2];
    #pragma unroll
    for (int g = 0; g < 2; ++g)
      #pragma unroll
      for (int kh = 0; kh < 2; ++kh)
        av[g][kh] = *(const bf16x8*)&A2[ks & 1][(((wr * 2 + g) * 2 + kh) * 512) + l * 8];
    float b[2][8];
    #pragma unroll
    for (int kh = 0; kh < 2; ++kh) {
      int bi = (kh * 16 + hi * 8) * 64 + wc * 32 + lo;
      #pragma unroll
      for (int q = 0; q < 8; ++q) b[kh][q] = B2[ks & 1][bi + q * 64];
    }
    lgkm0_bar();
    if (ks + 2 < NT) STAGE(ks & 1, (ks + 2) * BKD);

    bf16x8 bv[2];
    #pragma unroll
    for (int kh = 0; kh < 2; ++kh)
      #pragma unroll
      for (int q = 0; q < 8; ++q) bv[kh][q] = (__bf16)b[kh][q];
    #pragma unroll
    for (int kh = 0; kh < 2; ++kh)
      #pragma unroll
      for (int g = 0; g < 2; ++g)
        acc[g] = __builtin_amdgcn_mfma_f32_32x32x16_bf16(av[g][kh], bv[kh], acc[g], 0, 0, 0);
  }

  #pragma unroll
  for (int g = 0; g < 2; ++g)
    #pragma unroll
    for (int r = 0; r < 16; ++r) {
      int rl = mc * 128 + wr * 64 + g * 32 + (r & 3) + 8 * (r >> 2) + 4 * hi;
      if (rl < Me)
        os[(size_t)(rs + rl) * EMBD + nb + wc * 32 + lo] = (OS_T)acc[g][r];
    }
}

// ---------------- combine: out[t] = w1*os[r1] + w2*os[r2] ----------------
template <typename OS_T>
__global__ __launch_bounds__(256) void combine_k(
    const OS_T* __restrict__ os, const int* __restrict__ f2r,
    const float* __restrict__ wf, float* __restrict__ out) {
  int t = blockIdx.x;
  int c = threadIdx.x * 4;
  int r0 = f2r[2 * t], r1 = f2r[2 * t + 1];
  float wa = wf[2 * t], wb = wf[2 * t + 1];
  const OS_T* pa = os + (size_t)r0 * EMBD + c;
  const OS_T* pb = os + (size_t)r1 * EMBD + c;
  float4 o;
  o.x = wa * (float)pa[0] + wb * (float)pb[0];
  o.y = wa * (float)pa[1] + wb * (float)pb[1];
  o.z = wa * (float)pa[2] + wb * (float)pb[2];
  o.w = wa * (float)pa[3] + wb * (float)pb[3];
  *(float4*)(out + (size_t)t * EMBD + c) = o;
}

// ---------------- launcher ----------------
extern "C" void kernel_launch(void* const* d_in, const int* in_sizes, int n_in,
                              void* d_out, int out_size, void* d_ws, size_t ws_size,
                              hipStream_t stream) {
  const float* x  = (const float*)d_in[0];
  const float* gk = (const float*)d_in[1];
  const float* w0 = (const float*)d_in[2];
  const float* w1 = (const float*)d_in[3];
  const float* wo = (const float*)d_in[4];
  float* out = (float*)d_out;
  char* ws = (char*)d_ws;

  int*   counts = (int*)(ws + OFF_COUNTS);
  int*   basep  = (int*)(ws + OFF_BASE);
  int*   run    = (int*)(ws + OFF_RUN);
  int*   ef     = (int*)(ws + OFF_EFLAT);
  float* wfl    = (float*)(ws + OFF_WFLAT);
  int*   rowtok = (int*)(ws + OFF_ROWTOK);
  int*   f2r    = (int*)(ws + OFF_F2R);
  __hip_bfloat16* inter = (__hip_bfloat16*)(ws + OFF_INTER);

  hipMemsetAsync(ws, 0, 1024, stream);
  router_topk<<<NTOK / 4, 256, 0, stream>>>(x, gk, ef, wfl);
  hist_k<<<NFLAT / 256, 256, 0, stream>>>(ef, counts);
  scan_k<<<1, 64, 0, stream>>>(counts, basep);
  scatter_k<<<NFLAT / 256, 256, 0, stream>>>(ef, basep, run, rowtok, f2r);
  gemm1_k<<<dim3(MLPD / 64, MAXCH, NEXP), 256, 0, stream>>>(x, w0, w1, counts, basep, rowtok, inter);

  if (ws_size >= NEED_F32) {
    float* os = (float*)(ws + OFF_OS);
    gemm2_k<float><<<dim3(EMBD / 64, MAXCH, NEXP), 256, 0, stream>>>(inter, wo, counts, basep, os);
    combine_k<float><<<NTOK, 256, 0, stream>>>(os, f2r, wfl, out);
  } else {
    __hip_bfloat16* os = (__hip_bfloat16*)(ws + OFF_OS);
    gemm2_k<__hip_bfloat16><<<dim3(EMBD / 64, MAXCH, NEXP), 256, 0, stream>>>(inter, wo, counts, basep, os);
    combine_k<__hip_bfloat16><<<NTOK, 256, 0, stream>>>(os, f2r, wfl, out);
  }
}